// Round 13
// baseline (34.957 us; speedup 1.0000x reference)
//
#include <hip/hip_runtime.h>

#define EPS 1e-7f
#define NB 64
#define NI 1152
#define NJ 8
#define NK 43
#define NL 16
#define KL (NK*NL)        // 688
#define NSLICE 8
#define SLICE 144         // NI / NSLICE
#define THREADS 384
#define NKG 11            // groups of 4 k's (44 = NK+1 pad)
#define CPS 148           // float4 row stride for cP (144 + 4 pad)
#define PARTS 344         // NK*NJ
#define WVSZ 352          // NJ*44
#define SVP 17            // sV padded row stride (floats, odd -> conflict-free)
#define SPIN_LIMIT 200000000u

// ---- fused squash: s-values for one k-row live in a 16-lane group ----
__device__ __forceinline__ float squash_scale(float sv) {
    float sq = sv * sv;
    sq += __shfl_xor(sq, 1);
    sq += __shfl_xor(sq, 2);
    sq += __shfl_xor(sq, 4);
    sq += __shfl_xor(sq, 8);
    const float scale = sq / ((1.f + sq) * sqrtf(sq + EPS));
    return scale * sv;
}

// ---- main phase: per-i softmax (A) then register-blocked G + shuffle reduce (B) ----
// Partials written as relaxed AGENT-scope atomic stores (straight to coherent
// point, no cache-maintenance) so sibling blocks can read them fence-free.
__device__ __forceinline__ void routing_main(
    int tid, const float4* sXa, const float4* sXb,
    const float* sWv, float4* cP, float* __restrict__ gpOut)
{
    // Phase A: logits + softmax for this slice's 144 i's (one i per thread)
    if (tid < SLICE) {
        float4 x0 = sXa[tid], x1 = sXb[tid];
        float xr[NJ] = {x0.x, x0.y, x0.z, x0.w, x1.x, x1.y, x1.z, x1.w};
        float a[44];
        #pragma unroll
        for (int k = 0; k < 44; ++k) a[k] = 0.f;
        #pragma unroll
        for (int j = 0; j < NJ; ++j) {
            #pragma unroll
            for (int k4 = 0; k4 < NKG; ++k4) {
                float4 wv = *(const float4*)&sWv[j*44 + k4*4];
                a[k4*4+0] = fmaf(xr[j], wv.x, a[k4*4+0]);
                a[k4*4+1] = fmaf(xr[j], wv.y, a[k4*4+1]);
                a[k4*4+2] = fmaf(xr[j], wv.z, a[k4*4+2]);
                a[k4*4+3] = fmaf(xr[j], wv.w, a[k4*4+3]);
            }
        }
        float m0=a[0], m1=a[1], m2=a[2], m3=a[3];
        #pragma unroll
        for (int k = 4; k < 40; k += 4) {
            m0 = fmaxf(m0, a[k+0]); m1 = fmaxf(m1, a[k+1]);
            m2 = fmaxf(m2, a[k+2]); m3 = fmaxf(m3, a[k+3]);
        }
        m0 = fmaxf(m0, a[40]); m1 = fmaxf(m1, a[41]); m2 = fmaxf(m2, a[42]);
        const float m = fmaxf(fmaxf(m0, m1), fmaxf(m2, m3));
        float z0=0.f, z1=0.f, z2=0.f, z3=0.f;
        #pragma unroll
        for (int k = 0; k < 40; k += 4) {
            a[k+0] = __expf(a[k+0]-m); z0 += a[k+0];
            a[k+1] = __expf(a[k+1]-m); z1 += a[k+1];
            a[k+2] = __expf(a[k+2]-m); z2 += a[k+2];
            a[k+3] = __expf(a[k+3]-m); z3 += a[k+3];
        }
        a[40] = __expf(a[40]-m); z0 += a[40];
        a[41] = __expf(a[41]-m); z1 += a[41];
        a[42] = __expf(a[42]-m); z2 += a[42];
        const float inv = 1.f / ((z0+z1) + (z2+z3));
        #pragma unroll
        for (int k = 0; k < NK; ++k) a[k] *= inv;
        a[43] = 0.f;
        #pragma unroll
        for (int kg = 0; kg < NKG; ++kg)
            cP[kg*CPS + tid] = make_float4(a[4*kg], a[4*kg+1], a[4*kg+2], a[4*kg+3]);
    }
    __syncthreads();   // cP ready
    // Phase B: 11 k-groups x 16 lanes; 9 i's per lane; butterfly reduce
    if (tid < NKG*16) {
        const int kg = tid >> 4, s = tid & 15;
        float acc[4][8];
        #pragma unroll
        for (int q = 0; q < 4; ++q)
            #pragma unroll
            for (int j = 0; j < 8; ++j) acc[q][j] = 0.f;
        #pragma unroll
        for (int ii = 0; ii < SLICE/16; ++ii) {
            const int il = s + 16*ii;
            float4 c4 = cP[kg*CPS + il];
            float4 xa = sXa[il], xb = sXb[il];
            acc[0][0]=fmaf(c4.x,xa.x,acc[0][0]); acc[0][1]=fmaf(c4.x,xa.y,acc[0][1]);
            acc[0][2]=fmaf(c4.x,xa.z,acc[0][2]); acc[0][3]=fmaf(c4.x,xa.w,acc[0][3]);
            acc[0][4]=fmaf(c4.x,xb.x,acc[0][4]); acc[0][5]=fmaf(c4.x,xb.y,acc[0][5]);
            acc[0][6]=fmaf(c4.x,xb.z,acc[0][6]); acc[0][7]=fmaf(c4.x,xb.w,acc[0][7]);
            acc[1][0]=fmaf(c4.y,xa.x,acc[1][0]); acc[1][1]=fmaf(c4.y,xa.y,acc[1][1]);
            acc[1][2]=fmaf(c4.y,xa.z,acc[1][2]); acc[1][3]=fmaf(c4.y,xa.w,acc[1][3]);
            acc[1][4]=fmaf(c4.y,xb.x,acc[1][4]); acc[1][5]=fmaf(c4.y,xb.y,acc[1][5]);
            acc[1][6]=fmaf(c4.y,xb.z,acc[1][6]); acc[1][7]=fmaf(c4.y,xb.w,acc[1][7]);
            acc[2][0]=fmaf(c4.z,xa.x,acc[2][0]); acc[2][1]=fmaf(c4.z,xa.y,acc[2][1]);
            acc[2][2]=fmaf(c4.z,xa.z,acc[2][2]); acc[2][3]=fmaf(c4.z,xa.w,acc[2][3]);
            acc[2][4]=fmaf(c4.z,xb.x,acc[2][4]); acc[2][5]=fmaf(c4.z,xb.y,acc[2][5]);
            acc[2][6]=fmaf(c4.z,xb.z,acc[2][6]); acc[2][7]=fmaf(c4.z,xb.w,acc[2][7]);
            acc[3][0]=fmaf(c4.w,xa.x,acc[3][0]); acc[3][1]=fmaf(c4.w,xa.y,acc[3][1]);
            acc[3][2]=fmaf(c4.w,xa.z,acc[3][2]); acc[3][3]=fmaf(c4.w,xa.w,acc[3][3]);
            acc[3][4]=fmaf(c4.w,xb.x,acc[3][4]); acc[3][5]=fmaf(c4.w,xb.y,acc[3][5]);
            acc[3][6]=fmaf(c4.w,xb.z,acc[3][6]); acc[3][7]=fmaf(c4.w,xb.w,acc[3][7]);
        }
        float cur[32];
        #pragma unroll
        for (int q = 0; q < 4; ++q)
            #pragma unroll
            for (int j = 0; j < 8; ++j) cur[q*8+j] = acc[q][j];
        {   const bool up = (tid & 8) != 0;
            #pragma unroll
            for (int v = 0; v < 16; ++v) {
                float give = up ? cur[v] : cur[v+16];
                float keep = up ? cur[v+16] : cur[v];
                cur[v] = keep + __shfl_xor(give, 8);
            } }
        {   const bool up = (tid & 4) != 0;
            #pragma unroll
            for (int v = 0; v < 8; ++v) {
                float give = up ? cur[v] : cur[v+8];
                float keep = up ? cur[v+8] : cur[v];
                cur[v] = keep + __shfl_xor(give, 4);
            } }
        {   const bool up = (tid & 2) != 0;
            #pragma unroll
            for (int v = 0; v < 4; ++v) {
                float give = up ? cur[v] : cur[v+4];
                float keep = up ? cur[v+4] : cur[v];
                cur[v] = keep + __shfl_xor(give, 2);
            } }
        {   const bool up = (tid & 1) != 0;
            #pragma unroll
            for (int v = 0; v < 2; ++v) {
                float give = up ? cur[v] : cur[v+2];
                float keep = up ? cur[v+2] : cur[v];
                cur[v] = keep + __shfl_xor(give, 1);
            } }
        const int p = kg*32 + (s << 1);   // = k*8+j for v=2s
        if (p < PARTS) {
            __hip_atomic_store(&gpOut[p],   cur[0], __ATOMIC_RELAXED, __HIP_MEMORY_SCOPE_AGENT);
            __hip_atomic_store(&gpOut[p+1], cur[1], __ATOMIC_RELAXED, __HIP_MEMORY_SCOPE_AGENT);
        }
    }
}

// ---------- fully fused kernel: 8 slice-blocks per batch, fence-free barriers ----------
__global__ __launch_bounds__(THREADS, 3)
void caps_all(const float* __restrict__ X, const float* __restrict__ W,
              float* __restrict__ gp1, float* __restrict__ gp2,
              int* __restrict__ cnt1, int* __restrict__ cnt2,
              float* __restrict__ out) {
    __shared__ __align__(16) float4 sXa[SLICE], sXb[SLICE];
    __shared__ __align__(16) float4 cP[NKG*CPS];
    __shared__ __align__(16) float sWv[WVSZ];
    __shared__ __align__(16) float sV[NK*SVP];
    __shared__ float sG[PARTS];
    __shared__ __align__(16) float4 xsW[12];
    __shared__ float sXs[NJ];
    __shared__ int sLast;

    const int tid = threadIdx.x;
    const int b  = blockIdx.x >> 3;
    const int sl = blockIdx.x & 7;
    const float* Xb = X + (size_t)b * (NI*NJ);

    // ---- load this block's X slice into two float4 planes ----
    if (tid < SLICE*2) {
        const float4* Xs4 = (const float4*)(Xb + (size_t)sl*SLICE*NJ);
        float4 v = Xs4[tid];
        if (tid & 1) sXb[tid >> 1] = v; else sXa[tid >> 1] = v;
    }
    // ---- xs over full X (redundant per block; L2-served) ----
    {
        const float4* X4 = (const float4*)Xb;
        float4 ax = X4[tid];
        #pragma unroll
        for (int r = 1; r < 6; ++r) {
            float4 v = X4[tid + r*THREADS];
            ax.x += v.x; ax.y += v.y; ax.z += v.z; ax.w += v.w;
        }
        #pragma unroll
        for (int msk = 2; msk <= 32; msk <<= 1) {
            ax.x += __shfl_xor(ax.x, msk);
            ax.y += __shfl_xor(ax.y, msk);
            ax.z += __shfl_xor(ax.z, msk);
            ax.w += __shfl_xor(ax.w, msk);
        }
        if ((tid & 63) < 2) xsW[(tid >> 6)*2 + (tid & 1)] = ax;
    }
    __syncthreads();
    if (tid < NJ) {
        const float* f = (const float*)xsW;
        float s = 0.f;
        #pragma unroll
        for (int w = 0; w < 6; ++w) s += f[(w*2 + (tid >> 2))*4 + (tid & 3)];
        sXs[tid] = s;
    }
    __syncthreads();
    // ---- fused s0 -> squash -> v0 ----
    for (int t = tid; t < KL; t += THREADS) {
        float sv = 0.f;
        #pragma unroll
        for (int j = 0; j < NJ; ++j) sv = fmaf(sXs[j], W[j*KL + t], sv);
        sv *= (1.0f/43.0f);
        sV[(t >> 4)*SVP + (t & 15)] = squash_scale(sv);
    }
    __syncthreads();
    // ---- Wv0 (stays in LDS across both passes) ----
    if (tid < WVSZ) {
        const int j = tid / 44, k = tid % 44;
        float wv = 0.f;
        if (k < NK) {
            #pragma unroll
            for (int l = 0; l < NL; ++l)
                wv = fmaf(W[j*KL + k*NL + l], sV[k*SVP + l], wv);
        }
        sWv[tid] = wv;
    }
    __syncthreads();

    // ================= pass 1 =================
    routing_main(tid, sXa, sXb, sWv, cP, gp1 + (size_t)(b*NSLICE + sl)*PARTS);

    // ---- fence-free ALL-blocks barrier (8 blocks of batch b) ----
    asm volatile("s_waitcnt vmcnt(0)" ::: "memory");  // my atomic stores at coherent point
    __syncthreads();
    if (tid == 0) {
        __hip_atomic_fetch_add(&cnt1[b], 1, __ATOMIC_RELAXED, __HIP_MEMORY_SCOPE_AGENT);
        unsigned spins = 0;
        while (__hip_atomic_load(&cnt1[b], __ATOMIC_RELAXED, __HIP_MEMORY_SCOPE_AGENT) < NSLICE
               && ++spins < SPIN_LIMIT)
            __builtin_amdgcn_s_sleep(1);
    }
    __syncthreads();
    // ---- every block: reduce partials -> G1 -> v1 -> WvAcc (redundant, tiny) ----
    if (tid < PARTS) {
        float g = 0.f;
        #pragma unroll
        for (int q = 0; q < NSLICE; ++q)
            g += __hip_atomic_load(&gp1[(size_t)(b*NSLICE + q)*PARTS + tid],
                                   __ATOMIC_RELAXED, __HIP_MEMORY_SCOPE_AGENT);
        sG[tid] = g;
    }
    __syncthreads();
    for (int t = tid; t < KL; t += THREADS) {
        const int k8 = (t >> 4)*8;
        float sv = 0.f;
        #pragma unroll
        for (int j = 0; j < NJ; ++j) sv = fmaf(sG[k8 + j], W[j*KL + t], sv);
        sV[(t >> 4)*SVP + (t & 15)] = squash_scale(sv);
    }
    __syncthreads();
    if (tid < WVSZ) {
        const int j = tid / 44, k = tid % 44;
        float wv = 0.f;
        if (k < NK) {
            #pragma unroll
            for (int l = 0; l < NL; ++l)
                wv = fmaf(W[j*KL + k*NL + l], sV[k*SVP + l], wv);
        }
        sWv[tid] += wv;
    }
    __syncthreads();

    // ================= pass 2 =================
    routing_main(tid, sXa, sXb, sWv, cP, gp2 + (size_t)(b*NSLICE + sl)*PARTS);

    // ---- last-block fixup (R12-validated protocol) ----
    asm volatile("s_waitcnt vmcnt(0)" ::: "memory");
    __syncthreads();
    if (tid == 0) {
        int old = __hip_atomic_fetch_add(&cnt2[b], 1, __ATOMIC_RELAXED, __HIP_MEMORY_SCOPE_AGENT);
        sLast = (old == NSLICE - 1) ? 1 : 0;
    }
    __syncthreads();
    if (!sLast) return;
    if (tid < PARTS) {
        float g = 0.f;
        #pragma unroll
        for (int q = 0; q < NSLICE; ++q)
            g += __hip_atomic_load(&gp2[(size_t)(b*NSLICE + q)*PARTS + tid],
                                   __ATOMIC_RELAXED, __HIP_MEMORY_SCOPE_AGENT);
        sG[tid] = g;
    }
    __syncthreads();
    for (int t = tid; t < KL; t += THREADS) {
        const int k8 = (t >> 4)*8;
        float sv = 0.f;
        #pragma unroll
        for (int j = 0; j < NJ; ++j) sv = fmaf(sG[k8 + j], W[j*KL + t], sv);
        out[(size_t)b*KL + t] = squash_scale(sv);
    }
}

extern "C" void kernel_launch(void* const* d_in, const int* in_sizes, int n_in,
                              void* d_out, int out_size, void* d_ws, size_t ws_size,
                              hipStream_t stream) {
    const float* X = (const float*)d_in[0];   // [64,1152,8]
    const float* W = (const float*)d_in[1];   // [8,43,16]
    float* out = (float*)d_out;               // [64,43,16]
    float* gp1 = (float*)d_ws;                // [64][8][344]
    float* gp2 = gp1 + NB*NSLICE*PARTS;       // [64][8][344]
    int*   cnt = (int*)(gp2 + NB*NSLICE*PARTS);   // cnt1[64] ++ cnt2[64]
    hipMemsetAsync(cnt, 0, 2*NB*sizeof(int), stream);   // zero counters every call
    hipLaunchKernelGGL(caps_all, dim3(NB*NSLICE), dim3(THREADS), 0, stream,
                       X, W, gp1, gp2, cnt, cnt + NB, out);
}

// Round 14
// 24.953 us; speedup vs baseline: 1.4009x; 1.4009x over previous
//
#include <hip/hip_runtime.h>

#define EPS 1e-7f
#define NB 64
#define NI 1152
#define NJ 8
#define NK 43
#define NL 16
#define KL (NK*NL)        // 688
#define NSLICE 8
#define SLICE 144         // NI / NSLICE
#define THREADS 384
#define NKG 11            // groups of 4 k's (44 = NK+1 pad)
#define CPS 148           // float4 row stride for cP (144 + 4 pad)
#define PARTS 344         // NK*NJ
#define WVSZ 352          // NJ*44
#define SVP 17            // sV padded row stride (floats, odd -> conflict-free)

// ---- load this block's 144-row X slice into two float4 planes ----
__device__ __forceinline__ void load_slice(int tid, const float* __restrict__ Xb, int sl,
                                           float4* sXa, float4* sXb) {
    if (tid < SLICE*2) {
        const float4* Xs4 = (const float4*)(Xb + (size_t)sl*SLICE*NJ);
        float4 v = Xs4[tid];
        if (tid & 1) sXb[tid >> 1] = v; else sXa[tid >> 1] = v;
    }
}

// ---- fused squash: s-values for one k-row live in a 16-lane group,
//      returns scale[k]*sv via intra-group shuffle reduction of sum(s^2) ----
__device__ __forceinline__ float squash_scale(float sv) {
    float sq = sv * sv;
    sq += __shfl_xor(sq, 1);
    sq += __shfl_xor(sq, 2);
    sq += __shfl_xor(sq, 4);
    sq += __shfl_xor(sq, 8);
    const float scale = sq / ((1.f + sq) * sqrtf(sq + EPS));
    return scale * sv;
}

// ---- main phase: per-i softmax (A) then register-blocked G + shuffle reduce (B) ----
__device__ __forceinline__ void routing_main(
    int tid, const float4* sXa, const float4* sXb,
    const float (*sWv)[44], float4* cP, float* __restrict__ gpOut)
{
    // Phase A: logits + softmax for this slice's 144 i's (one i per thread)
    if (tid < SLICE) {
        float4 x0 = sXa[tid], x1 = sXb[tid];
        float xr[NJ] = {x0.x, x0.y, x0.z, x0.w, x1.x, x1.y, x1.z, x1.w};
        float a[44];
        #pragma unroll
        for (int k = 0; k < 44; ++k) a[k] = 0.f;
        #pragma unroll
        for (int j = 0; j < NJ; ++j) {
            #pragma unroll
            for (int k4 = 0; k4 < NKG; ++k4) {
                float4 wv = *(const float4*)&sWv[j][k4*4];
                a[k4*4+0] = fmaf(xr[j], wv.x, a[k4*4+0]);
                a[k4*4+1] = fmaf(xr[j], wv.y, a[k4*4+1]);
                a[k4*4+2] = fmaf(xr[j], wv.z, a[k4*4+2]);
                a[k4*4+3] = fmaf(xr[j], wv.w, a[k4*4+3]);
            }
        }
        float m0=a[0], m1=a[1], m2=a[2], m3=a[3];
        #pragma unroll
        for (int k = 4; k < 40; k += 4) {
            m0 = fmaxf(m0, a[k+0]); m1 = fmaxf(m1, a[k+1]);
            m2 = fmaxf(m2, a[k+2]); m3 = fmaxf(m3, a[k+3]);
        }
        m0 = fmaxf(m0, a[40]); m1 = fmaxf(m1, a[41]); m2 = fmaxf(m2, a[42]);
        const float m = fmaxf(fmaxf(m0, m1), fmaxf(m2, m3));
        float z0=0.f, z1=0.f, z2=0.f, z3=0.f;
        #pragma unroll
        for (int k = 0; k < 40; k += 4) {
            a[k+0] = __expf(a[k+0]-m); z0 += a[k+0];
            a[k+1] = __expf(a[k+1]-m); z1 += a[k+1];
            a[k+2] = __expf(a[k+2]-m); z2 += a[k+2];
            a[k+3] = __expf(a[k+3]-m); z3 += a[k+3];
        }
        a[40] = __expf(a[40]-m); z0 += a[40];
        a[41] = __expf(a[41]-m); z1 += a[41];
        a[42] = __expf(a[42]-m); z2 += a[42];
        const float inv = 1.f / ((z0+z1) + (z2+z3));
        #pragma unroll
        for (int k = 0; k < NK; ++k) a[k] *= inv;
        a[43] = 0.f;
        #pragma unroll
        for (int kg = 0; kg < NKG; ++kg)
            cP[kg*CPS + tid] = make_float4(a[4*kg], a[4*kg+1], a[4*kg+2], a[4*kg+3]);
    }
    __syncthreads();   // cP ready
    // Phase B: 11 k-groups x 16 lanes; 9 i's per lane; reduce via butterfly
    if (tid < NKG*16) {
        const int kg = tid >> 4, s = tid & 15;
        float acc[4][8];
        #pragma unroll
        for (int q = 0; q < 4; ++q)
            #pragma unroll
            for (int j = 0; j < 8; ++j) acc[q][j] = 0.f;
        #pragma unroll
        for (int ii = 0; ii < SLICE/16; ++ii) {
            const int il = s + 16*ii;
            float4 c4 = cP[kg*CPS + il];
            float4 xa = sXa[il], xb = sXb[il];
            acc[0][0]=fmaf(c4.x,xa.x,acc[0][0]); acc[0][1]=fmaf(c4.x,xa.y,acc[0][1]);
            acc[0][2]=fmaf(c4.x,xa.z,acc[0][2]); acc[0][3]=fmaf(c4.x,xa.w,acc[0][3]);
            acc[0][4]=fmaf(c4.x,xb.x,acc[0][4]); acc[0][5]=fmaf(c4.x,xb.y,acc[0][5]);
            acc[0][6]=fmaf(c4.x,xb.z,acc[0][6]); acc[0][7]=fmaf(c4.x,xb.w,acc[0][7]);
            acc[1][0]=fmaf(c4.y,xa.x,acc[1][0]); acc[1][1]=fmaf(c4.y,xa.y,acc[1][1]);
            acc[1][2]=fmaf(c4.y,xa.z,acc[1][2]); acc[1][3]=fmaf(c4.y,xa.w,acc[1][3]);
            acc[1][4]=fmaf(c4.y,xb.x,acc[1][4]); acc[1][5]=fmaf(c4.y,xb.y,acc[1][5]);
            acc[1][6]=fmaf(c4.y,xb.z,acc[1][6]); acc[1][7]=fmaf(c4.y,xb.w,acc[1][7]);
            acc[2][0]=fmaf(c4.z,xa.x,acc[2][0]); acc[2][1]=fmaf(c4.z,xa.y,acc[2][1]);
            acc[2][2]=fmaf(c4.z,xa.z,acc[2][2]); acc[2][3]=fmaf(c4.z,xa.w,acc[2][3]);
            acc[2][4]=fmaf(c4.z,xb.x,acc[2][4]); acc[2][5]=fmaf(c4.z,xb.y,acc[2][5]);
            acc[2][6]=fmaf(c4.z,xb.z,acc[2][6]); acc[2][7]=fmaf(c4.z,xb.w,acc[2][7]);
            acc[3][0]=fmaf(c4.w,xa.x,acc[3][0]); acc[3][1]=fmaf(c4.w,xa.y,acc[3][1]);
            acc[3][2]=fmaf(c4.w,xa.z,acc[3][2]); acc[3][3]=fmaf(c4.w,xa.w,acc[3][3]);
            acc[3][4]=fmaf(c4.w,xb.x,acc[3][4]); acc[3][5]=fmaf(c4.w,xb.y,acc[3][5]);
            acc[3][6]=fmaf(c4.w,xb.z,acc[3][6]); acc[3][7]=fmaf(c4.w,xb.w,acc[3][7]);
        }
        // butterfly reduce across the 16 lanes: lane s ends with G for v=2s,2s+1
        float cur[32];
        #pragma unroll
        for (int q = 0; q < 4; ++q)
            #pragma unroll
            for (int j = 0; j < 8; ++j) cur[q*8+j] = acc[q][j];
        {   const bool up = (tid & 8) != 0;
            #pragma unroll
            for (int v = 0; v < 16; ++v) {
                float give = up ? cur[v] : cur[v+16];
                float keep = up ? cur[v+16] : cur[v];
                cur[v] = keep + __shfl_xor(give, 8);
            } }
        {   const bool up = (tid & 4) != 0;
            #pragma unroll
            for (int v = 0; v < 8; ++v) {
                float give = up ? cur[v] : cur[v+8];
                float keep = up ? cur[v+8] : cur[v];
                cur[v] = keep + __shfl_xor(give, 4);
            } }
        {   const bool up = (tid & 2) != 0;
            #pragma unroll
            for (int v = 0; v < 4; ++v) {
                float give = up ? cur[v] : cur[v+4];
                float keep = up ? cur[v+4] : cur[v];
                cur[v] = keep + __shfl_xor(give, 2);
            } }
        {   const bool up = (tid & 1) != 0;
            #pragma unroll
            for (int v = 0; v < 2; ++v) {
                float give = up ? cur[v] : cur[v+2];
                float keep = up ? cur[v+2] : cur[v];
                cur[v] = keep + __shfl_xor(give, 1);
            } }
        const int p = kg*32 + (s << 1);   // = k*8+j for v=2s
        if (p < PARTS)
            *(float2*)&gpOut[p] = make_float2(cur[0], cur[1]);
    }
}

// ---------- K1: prologue (xs->v0->Wv0) + pass-1 main ----------
__global__ __launch_bounds__(THREADS, 3)
void caps_k1(const float* __restrict__ X, const float* __restrict__ W,
             float* __restrict__ wv0g, float* __restrict__ gp1) {
    __shared__ __align__(16) float4 sXa[SLICE], sXb[SLICE];
    __shared__ __align__(16) float4 cP[NKG*CPS];
    __shared__ __align__(16) float sWv[NJ][44];
    __shared__ __align__(16) float sV[NK*SVP];
    __shared__ __align__(16) float4 xsW[12];
    __shared__ float sXs[NJ];

    const int tid = threadIdx.x;
    const int b  = blockIdx.x >> 3;
    const int sl = blockIdx.x & 7;
    const float* Xb = X + (size_t)b * (NI*NJ);

    load_slice(tid, Xb, sl, sXa, sXb);
    // xs: coalesced float4 accumulation over full X (even tid: j0-3, odd tid: j4-7)
    {
        const float4* X4 = (const float4*)Xb;
        float4 ax = X4[tid];
        #pragma unroll
        for (int r = 1; r < 6; ++r) {
            float4 v = X4[tid + r*THREADS];
            ax.x += v.x; ax.y += v.y; ax.z += v.z; ax.w += v.w;
        }
        #pragma unroll
        for (int msk = 2; msk <= 32; msk <<= 1) {
            ax.x += __shfl_xor(ax.x, msk);
            ax.y += __shfl_xor(ax.y, msk);
            ax.z += __shfl_xor(ax.z, msk);
            ax.w += __shfl_xor(ax.w, msk);
        }
        if ((tid & 63) < 2) xsW[(tid >> 6)*2 + (tid & 1)] = ax;
    }
    __syncthreads();
    if (tid < NJ) {
        const float* f = (const float*)xsW;
        float s = 0.f;
        #pragma unroll
        for (int w = 0; w < 6; ++w) s += f[(w*2 + (tid >> 2))*4 + (tid & 3)];
        sXs[tid] = s;
    }
    __syncthreads();
    // fused s0 -> squash -> v0
    for (int t = tid; t < KL; t += THREADS) {
        float sv = 0.f;
        #pragma unroll
        for (int j = 0; j < NJ; ++j) sv = fmaf(sXs[j], W[j*KL + t], sv);
        sv *= (1.0f/43.0f);
        sV[(t >> 4)*SVP + (t & 15)] = squash_scale(sv);
    }
    __syncthreads();
    // Wv0[j,k]; slice 0 persists for K2
    if (tid < WVSZ) {
        const int j = tid / 44, k = tid % 44;
        float wv = 0.f;
        if (k < NK) {
            #pragma unroll
            for (int l = 0; l < NL; ++l)
                wv = fmaf(W[j*KL + k*NL + l], sV[k*SVP + l], wv);
        }
        ((float*)sWv)[tid] = wv;
        if (sl == 0) wv0g[(size_t)b*WVSZ + tid] = wv;
    }
    __syncthreads();
    routing_main(tid, sXa, sXb, sWv, cP, gp1 + (size_t)(b*NSLICE + sl)*PARTS);
}

// ---------- K2: pass-1 tail (G1->v1->WvAcc) + pass-2 main ----------
__global__ __launch_bounds__(THREADS, 3)
void caps_k2(const float* __restrict__ X, const float* __restrict__ W,
             const float* __restrict__ wv0g, const float* __restrict__ gp1,
             float* __restrict__ gp2) {
    __shared__ __align__(16) float4 sXa[SLICE], sXb[SLICE];
    __shared__ __align__(16) float4 cP[NKG*CPS];
    __shared__ __align__(16) float sWv[NJ][44];
    __shared__ __align__(16) float sV[NK*SVP];
    __shared__ float sG[PARTS];

    const int tid = threadIdx.x;
    const int b  = blockIdx.x >> 3;
    const int sl = blockIdx.x & 7;
    const float* Xb = X + (size_t)b * (NI*NJ);

    load_slice(tid, Xb, sl, sXa, sXb);
    if (tid < PARTS) {
        float g = 0.f;
        #pragma unroll
        for (int q = 0; q < NSLICE; ++q) g += gp1[(size_t)(b*NSLICE + q)*PARTS + tid];
        sG[tid] = g;
    }
    __syncthreads();
    // fused s1 -> squash -> v1
    for (int t = tid; t < KL; t += THREADS) {
        const int k8 = (t >> 4)*8;
        float sv = 0.f;
        #pragma unroll
        for (int j = 0; j < NJ; ++j) sv = fmaf(sG[k8 + j], W[j*KL + t], sv);
        sV[(t >> 4)*SVP + (t & 15)] = squash_scale(sv);
    }
    __syncthreads();
    // WvAcc = Wv0 + Wv1
    if (tid < WVSZ) {
        const int j = tid / 44, k = tid % 44;
        float wv = 0.f;
        if (k < NK) {
            #pragma unroll
            for (int l = 0; l < NL; ++l)
                wv = fmaf(W[j*KL + k*NL + l], sV[k*SVP + l], wv);
        }
        ((float*)sWv)[tid] = wv0g[(size_t)b*WVSZ + tid] + wv;
    }
    __syncthreads();
    routing_main(tid, sXa, sXb, sWv, cP, gp2 + (size_t)(b*NSLICE + sl)*PARTS);
}

// ---------- K3: pass-2 tail (G2 -> s -> squash -> out), one barrier ----------
__global__ __launch_bounds__(THREADS, 1)
void caps_k3(const float* __restrict__ W, const float* __restrict__ gp2,
             float* __restrict__ out) {
    __shared__ float sG[PARTS];
    const int tid = threadIdx.x;
    const int b = blockIdx.x;
    if (tid < PARTS) {
        float g = 0.f;
        #pragma unroll
        for (int q = 0; q < NSLICE; ++q) g += gp2[(size_t)(b*NSLICE + q)*PARTS + tid];
        sG[tid] = g;
    }
    __syncthreads();
    for (int t = tid; t < KL; t += THREADS) {
        const int k8 = (t >> 4)*8;
        float sv = 0.f;
        #pragma unroll
        for (int j = 0; j < NJ; ++j) sv = fmaf(sG[k8 + j], W[j*KL + t], sv);
        out[(size_t)b*KL + t] = squash_scale(sv);
    }
}

extern "C" void kernel_launch(void* const* d_in, const int* in_sizes, int n_in,
                              void* d_out, int out_size, void* d_ws, size_t ws_size,
                              hipStream_t stream) {
    const float* X = (const float*)d_in[0];   // [64,1152,8]
    const float* W = (const float*)d_in[1];   // [8,43,16]
    float* out = (float*)d_out;               // [64,43,16]
    float* wv0 = (float*)d_ws;                // [64][352]
    float* gp1 = wv0 + NB*WVSZ;               // [64][8][344]
    float* gp2 = gp1 + NB*NSLICE*PARTS;       // [64][8][344]
    hipLaunchKernelGGL(caps_k1, dim3(NB*NSLICE), dim3(THREADS), 0, stream, X, W, wv0, gp1);
    hipLaunchKernelGGL(caps_k2, dim3(NB*NSLICE), dim3(THREADS), 0, stream, X, W, wv0, gp1, gp2);
    hipLaunchKernelGGL(caps_k3, dim3(NB), dim3(THREADS), 0, stream, W, gp2, out);
}